// Round 6
// baseline (336.263 us; speedup 1.0000x reference)
//
#include <hip/hip_runtime.h>

#define BATCH 64
#define SEQ 729
#define DIM 64
#define QT 12          // q tiles of 64
#define NKT 12         // k tiles of 64
#define KSPLIT 2       // k-split across blocks (occupancy lever)
#define KT (NKT / KSPLIT)
#define STRB 72        // bf16 LDS row stride (Ks/Vs/Qs): 144B rows, 16B-aligned
#define MSTR 68        // mask byte-row stride
#define OSTR 68        // epilogue fp32 dword-row stride

typedef __attribute__((ext_vector_type(8))) short bf16x8;
typedef __attribute__((ext_vector_type(4))) float f32x4;
// 4B-aligned vector views for the 729-strided global rows
typedef int   i32x4a __attribute__((ext_vector_type(4), aligned(4)));
typedef float f32x4a __attribute__((ext_vector_type(4), aligned(4)));

__device__ __forceinline__ unsigned short f2bf(float f) {
    unsigned int u = __float_as_uint(f);
    u += 0x7fffu + ((u >> 16) & 1u);   // round-to-nearest-even
    return (unsigned short)(u >> 16);
}

__device__ __forceinline__ unsigned long long pack4bf(float a, float b, float c, float d) {
    return (unsigned long long)f2bf(a)
         | ((unsigned long long)f2bf(b) << 16)
         | ((unsigned long long)f2bf(c) << 32)
         | ((unsigned long long)f2bf(d) << 48);
}

__device__ __forceinline__ float bf2f(unsigned int hi16) {
    return __uint_as_float(hi16 << 16);
}

// tanh(x) = 1 - 2/(exp2(2x*log2e)+1)
__device__ __forceinline__ float fast_tanh(float x) {
    float e = __builtin_amdgcn_exp2f(x * 2.88539008177792681f);
    return 1.0f - 2.0f * __builtin_amdgcn_rcpf(e + 1.0f);
}

// Raw barrier WITHOUT the __syncthreads() vmcnt(0) drain (round-5 win, keep):
// only LDS ops fenced; prefetch loads + attn stores stay in flight across
// phases; counted vmcnt at the register drain waits exactly what's needed.
#define BAR() do { \
    asm volatile("s_waitcnt lgkmcnt(0)" ::: "memory"); \
    __builtin_amdgcn_s_barrier(); \
    __builtin_amdgcn_sched_barrier(0); \
} while (0)

// launch_bounds(256,3): the ONLY config the allocator handles cleanly
// (84 VGPR, no scratch; rounds 1-4 showed (256,4)/(256,5) self-destruct).
// Residency is determined at runtime: VGPR 84 -> 6 waves/SIMD possible;
// LDS 32000B (rounds to 32256) -> floor(163840/32256) = 5 blocks/CU.
__global__ __launch_bounds__(256, 3) void attn_kernel(
    const float* __restrict__ Qg, const float* __restrict__ Kg,
    const float* __restrict__ Vg, const int* __restrict__ Mg,
    float* __restrict__ Og, float* __restrict__ Ag)
{
    __shared__ __align__(16) unsigned char smem[32000];
    unsigned short* Ks  = (unsigned short*)(smem);           // [k][d] bf16
    unsigned short* Vs  = (unsigned short*)(smem + 9216);    // [d][k] bf16 (transposed)
    unsigned short* Qs  = (unsigned short*)(smem + 18432);   // Q bf16, then P bf16 (wave-private rows)
    unsigned char*  Mb8 = smem + 27648;                      // [q][k] mask bytes
    float* Ostage = (float*)smem;   // epilogue overlay on Ks+Vs (17408 <= 18432)

    const int tid = threadIdx.x;
    const int q0  = blockIdx.x * 64;
    const int b   = blockIdx.y;
    const int kt0 = blockIdx.z * KT;          // this block's first k-tile

    const float* Qb = Qg + (size_t)b * SEQ * DIM;
    const float* Kb = Kg + (size_t)b * SEQ * DIM;
    const float* Vb = Vg + (size_t)b * SEQ * DIM;
    const int*   Mb = Mg + (size_t)b * SEQ * SEQ;
    float* Ob = Og + (size_t)b * SEQ * DIM;
    float* Ab = Ag + (size_t)b * SEQ * SEQ;

    const int lane = tid & 63;
    const int quad = lane >> 4;
    const int l15  = lane & 15;
    const int qrow = (tid >> 6) * 16;      // wave's q-strip base (local)

    // block-cooperative staging geometry: 16 consecutive threads cover one
    // row's 64 cols -> 256B contiguous segments, float4 per lane (KEEP:
    // round-1 showed 64B scalar segments amplify HBM traffic 5-10x)
    const int rr = tid >> 4;               // row group 0..15 (+16*i)
    const int cc = (tid & 15) * 4;         // col (floats)
    const int vd0 = (tid & 15) * 4;        // V: dims
    const int vk0 = (tid >> 4) * 4;        // V: k rows
    // wave-private mask/attn row geometry: 16 lanes cover one row's 64 cols
    const int prow = qrow + (lane >> 4);   // + 4*i -> rows qrow..qrow+15
    const int pcol = (lane & 15) * 4;

    float4 kr[4], vr[4];
    i32x4a mr[4];

    auto load_k = [&](int k0n) {
        #pragma unroll
        for (int i = 0; i < 4; ++i) {
            int gk = k0n + rr + 16 * i;
            kr[i] = (gk < SEQ) ? *(const float4*)(Kb + gk * DIM + cc)
                               : float4{0, 0, 0, 0};
        }
    };
    auto load_v = [&](int k0n) {
        #pragma unroll
        for (int i = 0; i < 4; ++i) {
            int gk = k0n + vk0 + i;
            vr[i] = (gk < SEQ) ? *(const float4*)(Vb + gk * DIM + vd0)
                               : float4{0, 0, 0, 0};
        }
    };
    auto load_mask = [&](int k0n) {
        #pragma unroll
        for (int i = 0; i < 4; ++i) {
            int gq = q0 + prow + 4 * i;
            int gk = k0n + pcol;
            if (gq < SEQ && gk + 3 < SEQ) {
                mr[i] = *(const i32x4a*)(Mb + (size_t)gq * SEQ + gk);
            } else if (gq < SEQ) {
                i32x4a t;
                #pragma unroll
                for (int e = 0; e < 4; ++e)
                    t[e] = (gk + e < SEQ) ? Mb[(size_t)gq * SEQ + gk + e] : 0;
                mr[i] = t;
            } else {
                mr[i] = i32x4a{0, 0, 0, 0};
            }
        }
    };
    auto drain_mask = [&]() {   // pack 0/1 ints to bytes; wave-private rows
        #pragma unroll
        for (int i = 0; i < 4; ++i) {
            unsigned int mb = (unsigned)(mr[i][0] & 1)
                            | ((unsigned)(mr[i][1] & 1) << 8)
                            | ((unsigned)(mr[i][2] & 1) << 16)
                            | ((unsigned)(mr[i][3] & 1) << 24);
            *(unsigned int*)&Mb8[(prow + 4 * i) * MSTR + pcol] = mb;
        }
    };
    auto drain_kv = [&]() {
        #pragma unroll
        for (int i = 0; i < 4; ++i)
            *(unsigned long long*)&Ks[(rr + 16 * i) * STRB + cc] =
                pack4bf(kr[i].x, kr[i].y, kr[i].z, kr[i].w);
        #pragma unroll
        for (int j = 0; j < 4; ++j) {
            float v0 = j==0?vr[0].x:j==1?vr[0].y:j==2?vr[0].z:vr[0].w;
            float v1 = j==0?vr[1].x:j==1?vr[1].y:j==2?vr[1].z:vr[1].w;
            float v2 = j==0?vr[2].x:j==1?vr[2].y:j==2?vr[2].z:vr[2].w;
            float v3 = j==0?vr[3].x:j==1?vr[3].y:j==2?vr[3].z:vr[3].w;
            *(unsigned long long*)&Vs[(vd0 + j) * STRB + vk0] = pack4bf(v0, v1, v2, v3);
        }
    };

    // ---- stage Q tile (256B-coalesced float4 loads) ----
    #pragma unroll
    for (int i = 0; i < 4; ++i) {
        int gq = q0 + rr + 16 * i;
        float4 x = (gq < SEQ) ? *(const float4*)(Qb + gq * DIM + cc)
                              : float4{0, 0, 0, 0};
        *(unsigned long long*)&Qs[(rr + 16 * i) * STRB + cc] = pack4bf(x.x, x.y, x.z, x.w);
    }
    BAR();   // release Qs (lgkmcnt only; no vmcnt drain)

    // hoist loop-invariant Q fragments; Qs becomes the P bf16 buffer
    const bf16x8 aq0 = *(const bf16x8*)&Qs[(qrow + l15) * STRB + quad * 8];
    const bf16x8 aq1 = *(const bf16x8*)&Qs[(qrow + l15) * STRB + 32 + quad * 8];

    // preload first tile into regs
    load_k(kt0 * 64); load_v(kt0 * 64); load_mask(kt0 * 64);

    f32x4 oacc[4];
    #pragma unroll
    for (int dt = 0; dt < 4; ++dt) {
        oacc[dt][0]=0.f; oacc[dt][1]=0.f; oacc[dt][2]=0.f; oacc[dt][3]=0.f;
    }

    for (int t = 0; t < KT; ++t) {
        const int k0 = (kt0 + t) * 64;

        BAR();                      // prev tile's Ks/Vs readers done (no vmcnt!)
        drain_mask();               // counted vmcnt: waits only this tile's loads
        drain_kv();
        BAR();                      // Ks/Vs staging visible (lgkmcnt release)

        // prefetch tile t+1 into regs (stays in flight across the barriers)
        if (t + 1 < KT) {
            load_k(k0 + 64); load_v(k0 + 64); load_mask(k0 + 64);
        }

        // ---- QK^T ----
        f32x4 sacc[4];
        #pragma unroll
        for (int n = 0; n < 4; ++n) {
            bf16x8 bk0 = *(const bf16x8*)&Ks[(n * 16 + l15) * STRB + quad * 8];
            bf16x8 bk1 = *(const bf16x8*)&Ks[(n * 16 + l15) * STRB + 32 + quad * 8];
            f32x4 c; c[0]=0.f; c[1]=0.f; c[2]=0.f; c[3]=0.f;
            c = __builtin_amdgcn_mfma_f32_16x16x32_bf16(aq0, bk0, c, 0, 0, 0);
            c = __builtin_amdgcn_mfma_f32_16x16x32_bf16(aq1, bk1, c, 0, 0, 0);
            sacc[n] = c;
        }

        // ---- scale, mask (LDS bytes), tanh, zero-diag; write P bf16 ----
        #pragma unroll
        for (int n = 0; n < 4; ++n) {
            int col = n * 16 + l15;
            int gk  = k0 + col;
            #pragma unroll
            for (int r = 0; r < 4; ++r) {
                int qloc = qrow + quad * 4 + r;
                int gq = q0 + qloc;
                int m = Mb8[qloc * MSTR + col];
                float sv = sacc[n][r] * 0.125f;       // 1/sqrt(64)
                bool msk = (m == 0);
                float p = fast_tanh(msk ? -1e9f : sv);
                if (msk) p = -1.0f;
                if (gq == gk) p = 0.0f;               // ignore_diag
                if (gq >= SEQ || gk >= SEQ) p = 0.0f; // padding
                Qs[qloc * STRB + col] = f2bf(p);
            }
        }

        // ---- attention write-out from bf16 P (same values PV consumes):
        //      wave-private rows, row-contiguous float4 -> 256B segments ----
        #pragma unroll
        for (int i = 0; i < 4; ++i) {
            int row = prow + 4 * i;
            int gq  = q0 + row;
            int gk  = k0 + pcol;
            unsigned long long w = *(const unsigned long long*)&Qs[row * STRB + pcol];
            f32x4 pv;
            pv[0] = bf2f((unsigned)(w      ) & 0xffffu);
            pv[1] = bf2f((unsigned)(w >> 16) & 0xffffu);
            pv[2] = bf2f((unsigned)(w >> 32) & 0xffffu);
            pv[3] = bf2f((unsigned)(w >> 48) & 0xffffu);
            if (gq < SEQ) {
                if (gk + 3 < SEQ) {
                    *(f32x4a*)(Ab + (size_t)gq * SEQ + gk) = pv;
                } else {
                    #pragma unroll
                    for (int e = 0; e < 4; ++e)
                        if (gk + e < SEQ) Ab[(size_t)gq * SEQ + gk + e] = pv[e];
                }
            }
        }

        // ---- PV ----
        const bf16x8 ap0 = *(const bf16x8*)&Qs[(qrow + l15) * STRB + quad * 8];
        const bf16x8 ap1 = *(const bf16x8*)&Qs[(qrow + l15) * STRB + 32 + quad * 8];
        #pragma unroll
        for (int dt = 0; dt < 4; ++dt) {
            bf16x8 bv0 = *(const bf16x8*)&Vs[(dt * 16 + l15) * STRB + quad * 8];
            bf16x8 bv1 = *(const bf16x8*)&Vs[(dt * 16 + l15) * STRB + 32 + quad * 8];
            oacc[dt] = __builtin_amdgcn_mfma_f32_16x16x32_bf16(ap0, bv0, oacc[dt], 0, 0, 0);
            oacc[dt] = __builtin_amdgcn_mfma_f32_16x16x32_bf16(ap1, bv1, oacc[dt], 0, 0, 0);
        }
    }

    // ---- O epilogue: all waves done with Ks/Vs -> overlay-stage, then
    //      ROW-LINEAR atomics (64 consecutive dwords = 256B per wave-instr) ----
    BAR();
    #pragma unroll
    for (int dt = 0; dt < 4; ++dt)
        #pragma unroll
        for (int r = 0; r < 4; ++r)
            Ostage[(qrow + quad * 4 + r) * OSTR + dt * 16 + l15] = oacc[dt][r];
    // wave-private strip: no further barrier needed
    #pragma unroll
    for (int r16 = 0; r16 < 16; ++r16) {
        int row = qrow + r16;
        int gq  = q0 + row;
        float val = Ostage[row * OSTR + lane];
        if (gq < SEQ)
            atomicAdd(Ob + (size_t)gq * DIM + lane, val);
    }
}

extern "C" void kernel_launch(void* const* d_in, const int* in_sizes, int n_in,
                              void* d_out, int out_size, void* d_ws, size_t ws_size,
                              hipStream_t stream) {
    const float* Q = (const float*)d_in[0];
    const float* K = (const float*)d_in[1];
    const float* V = (const float*)d_in[2];
    const int*   M = (const int*)d_in[3];
    float* Out  = (float*)d_out;
    float* Attn = Out + (size_t)BATCH * SEQ * DIM;   // tuple order: (out, attention)
    // zero O for cross-block k-split accumulation (async, graph-capture-safe)
    hipMemsetAsync(Out, 0, (size_t)BATCH * SEQ * DIM * sizeof(float), stream);
    dim3 grid(QT, BATCH, KSPLIT);
    attn_kernel<<<grid, 256, 0, stream>>>(Q, K, V, M, Out, Attn);
}

// Round 7
// 332.166 us; speedup vs baseline: 1.0123x; 1.0123x over previous
//
#include <hip/hip_runtime.h>

#define BATCH 64
#define SEQ 729
#define DIM 64
#define NT 12       // k tiles of 64
#define STRB 72     // Ks/Vs LDS row stride (shorts)
#define STRP 136    // Ps LDS row stride (shorts): 2 tiles wide + 8 pad
#define MCH 772     // mask chunk row stride (bytes): covers cols 0..767, +bank skew
#define OSTR 68     // epilogue fp32 dword-row stride

typedef __attribute__((ext_vector_type(8))) short bf16x8;
typedef __attribute__((ext_vector_type(4))) float f32x4;
// 4B-aligned vector views for the 729-strided global rows
typedef int   i32x4a __attribute__((ext_vector_type(4), aligned(4)));
typedef float f32x4a __attribute__((ext_vector_type(4), aligned(4)));

__device__ __forceinline__ unsigned short f2bf(float f) {
    unsigned int u = __float_as_uint(f);
    u += 0x7fffu + ((u >> 16) & 1u);   // round-to-nearest-even
    return (unsigned short)(u >> 16);
}

__device__ __forceinline__ unsigned long long pack4bf(float a, float b, float c, float d) {
    return (unsigned long long)f2bf(a)
         | ((unsigned long long)f2bf(b) << 16)
         | ((unsigned long long)f2bf(c) << 32)
         | ((unsigned long long)f2bf(d) << 48);
}

__device__ __forceinline__ float bf2f(unsigned int hi16) {
    return __uint_as_float(hi16 << 16);
}

// tanh(x) = 1 - 2/(exp2(2x*log2e)+1)
__device__ __forceinline__ float fast_tanh(float x) {
    float e = __builtin_amdgcn_exp2f(x * 2.88539008177792681f);
    return 1.0f - 2.0f * __builtin_amdgcn_rcpf(e + 1.0f);
}

// Raw barrier WITHOUT the __syncthreads() vmcnt(0) drain (round-5 win, keep):
// only LDS ops fenced; loads/stores stay in flight across phases; counted
// vmcnt at each register drain waits exactly what it needs.
#define BAR() do { \
    asm volatile("s_waitcnt lgkmcnt(0)" ::: "memory"); \
    __builtin_amdgcn_s_barrier(); \
    __builtin_amdgcn_sched_barrier(0); \
} while (0)

// launch_bounds(256,3): the only config the allocator handles cleanly
// (84 VGPR, no scratch — rounds 1-4 evidence). Residency set by runtime
// resources: LDS 35840B -> 4 blocks/CU; VGPR 84 -> 16 waves/CU -> 4 blocks.
__global__ __launch_bounds__(256, 3) void attn_kernel(
    const float* __restrict__ Qg, const float* __restrict__ Kg,
    const float* __restrict__ Vg, const int* __restrict__ Mg,
    float* __restrict__ Og, float* __restrict__ Ag)
{
    __shared__ __align__(16) unsigned char smem[35840];
    unsigned short* Ks = (unsigned short*)smem;            // [k][d] bf16 (9216)
    unsigned short* Vs = (unsigned short*)(smem + 9216);   // [d][k] bf16 (9216)
    unsigned short* Ps = (unsigned short*)(smem + 18432);  // Q bf16, then P bf16 2-tiles (17408)
    unsigned char*  Mc = smem;            // PROLOGUE overlay on Ks+Vs: mask chunk 16xMCH=12352
    float* Ostage = (float*)smem;         // EPILOGUE overlay on Ks+Vs: 64x68x4=17408

    const int tid = threadIdx.x;
    const int q0  = blockIdx.x * 64;
    const int b   = blockIdx.y;

    const float* Qb = Qg + (size_t)b * SEQ * DIM;
    const float* Kb = Kg + (size_t)b * SEQ * DIM;
    const float* Vb = Vg + (size_t)b * SEQ * DIM;
    const int*   Mb = Mg + (size_t)b * SEQ * SEQ;
    float* Ob = Og + (size_t)b * SEQ * DIM;
    float* Ab = Ag + (size_t)b * SEQ * SEQ;

    const int lane = tid & 63;
    const int quad = lane >> 4;
    const int l15  = lane & 15;
    const int wid  = tid >> 6;
    const int qrow = wid * 16;             // wave's q-strip base (local)

    // block-cooperative staging geometry: 16 consecutive threads cover one
    // row's 64 cols -> 256B contiguous segments, float4 per lane (KEEP:
    // round-1 showed smaller scalar segments amplify HBM traffic 5-10x)
    const int rr = tid >> 4;               // row group 0..15 (+16*i)
    const int cc = (tid & 15) * 4;         // col (floats)
    const int vd0 = (tid & 15) * 4;        // V: dims
    const int vk0 = (tid >> 4) * 4;        // V: k rows
    // wave-private row geometry (epilogue O): 16 lanes cover one row's 64 cols
    const int prow = qrow + (lane >> 4);   // + 4*i -> rows qrow..qrow+15
    const int pcol = (lane & 15) * 4;

    float4 kr[4], vr[4];

    auto load_k = [&](int k0n) {
        #pragma unroll
        for (int i = 0; i < 4; ++i) {
            int gk = k0n + rr + 16 * i;
            kr[i] = (gk < SEQ) ? *(const float4*)(Kb + gk * DIM + cc)
                               : float4{0, 0, 0, 0};
        }
    };
    auto load_v = [&](int k0n) {
        #pragma unroll
        for (int i = 0; i < 4; ++i) {
            int gk = k0n + vk0 + i;
            vr[i] = (gk < SEQ) ? *(const float4*)(Vb + gk * DIM + vd0)
                               : float4{0, 0, 0, 0};
        }
    };
    auto drain_kv = [&]() {
        #pragma unroll
        for (int i = 0; i < 4; ++i)
            *(unsigned long long*)&Ks[(rr + 16 * i) * STRB + cc] =
                pack4bf(kr[i].x, kr[i].y, kr[i].z, kr[i].w);
        #pragma unroll
        for (int j = 0; j < 4; ++j) {
            float v0 = j==0?vr[0].x:j==1?vr[0].y:j==2?vr[0].z:vr[0].w;
            float v1 = j==0?vr[1].x:j==1?vr[1].y:j==2?vr[1].z:vr[1].w;
            float v2 = j==0?vr[2].x:j==1?vr[2].y:j==2?vr[2].z:vr[2].w;
            float v3 = j==0?vr[3].x:j==1?vr[3].y:j==2?vr[3].z:vr[3].w;
            *(unsigned long long*)&Vs[(vd0 + j) * STRB + vk0] = pack4bf(v0, v1, v2, v3);
        }
    };

    // ---- prologue A: stage Q tile into Ps (256B-coalesced float4 loads) ----
    #pragma unroll
    for (int i = 0; i < 4; ++i) {
        int gq = q0 + rr + 16 * i;
        float4 x = (gq < SEQ) ? *(const float4*)(Qb + gq * DIM + cc)
                              : float4{0, 0, 0, 0};
        *(unsigned long long*)&Ps[(rr + 16 * i) * STRP + cc] = pack4bf(x.x, x.y, x.z, x.w);
    }

    // ---- prologue B: issue K/V tile-0 loads; they stay in flight across
    //      the whole mask prologue (counted vmcnt at phase-0 drain) ----
    load_k(0); load_v(0);

    // ---- prologue C: mask rows -> LDS chunks (FULL-ROW contiguous 2916B
    //      reads, DRAM-friendly) -> per-lane bit-pack into 6 VGPRs ----
    unsigned mb[6] = {0, 0, 0, 0, 0, 0};
    const int mg = tid >> 4;               // group = row within chunk
    const int ml = tid & 15;
    for (int c = 0; c < 4; ++c) {
        int grow = q0 + c * 16 + mg;
        #pragma unroll
        for (int it = 0; it < 12; ++it) {  // 12*64 = 768 cols (zero-pad tail)
            int col = it * 64 + ml * 4;
            i32x4a v = {0, 0, 0, 0};
            if (grow < SEQ) {
                if (col + 3 < SEQ) {
                    v = *(const i32x4a*)(Mb + (size_t)grow * SEQ + col);
                } else {
                    #pragma unroll
                    for (int e = 0; e < 4; ++e)
                        if (col + e < SEQ) v[e] = Mb[(size_t)grow * SEQ + col + e];
                }
            }
            unsigned by = (unsigned)(v[0] & 1) | ((unsigned)(v[1] & 1) << 8)
                        | ((unsigned)(v[2] & 1) << 16) | ((unsigned)(v[3] & 1) << 24);
            *(unsigned*)&Mc[mg * MCH + col] = by;
        }
        BAR();
        if (wid == c) {                    // wave c consumes its own chunk
            #pragma unroll
            for (int t = 0; t < 12; ++t)
                #pragma unroll
                for (int n = 0; n < 4; ++n)
                    #pragma unroll
                    for (int r = 0; r < 4; ++r)
                        if (Mc[(quad * 4 + r) * MCH + t * 64 + n * 16 + l15])
                            mb[t >> 1] |= 1u << ((t & 1) * 16 + n * 4 + r);
        }
        BAR();
    }

    // hoist loop-invariant Q fragments; Ps becomes the 2-tile P bf16 buffer
    const bf16x8 aq0 = *(const bf16x8*)&Ps[(qrow + l15) * STRP + quad * 8];
    const bf16x8 aq1 = *(const bf16x8*)&Ps[(qrow + l15) * STRP + 32 + quad * 8];

    f32x4 oacc[4];
    #pragma unroll
    for (int dt = 0; dt < 4; ++dt) {
        oacc[dt][0]=0.f; oacc[dt][1]=0.f; oacc[dt][2]=0.f; oacc[dt][3]=0.f;
    }

    auto phase = [&](int t, unsigned half16, int toff) {
        const int k0 = t * 64;

        BAR();                      // prev tile's Ks/Vs readers done (no vmcnt)
        drain_kv();                 // counted vmcnt: waits only K/V loads
        BAR();                      // staging visible (lgkmcnt release)

        if (t + 1 < NT) { load_k(k0 + 64); load_v(k0 + 64); }

        // ---- QK^T ----
        f32x4 sacc[4];
        #pragma unroll
        for (int n = 0; n < 4; ++n) {
            bf16x8 bk0 = *(const bf16x8*)&Ks[(n * 16 + l15) * STRB + quad * 8];
            bf16x8 bk1 = *(const bf16x8*)&Ks[(n * 16 + l15) * STRB + 32 + quad * 8];
            f32x4 cacc; cacc[0]=0.f; cacc[1]=0.f; cacc[2]=0.f; cacc[3]=0.f;
            cacc = __builtin_amdgcn_mfma_f32_16x16x32_bf16(aq0, bk0, cacc, 0, 0, 0);
            cacc = __builtin_amdgcn_mfma_f32_16x16x32_bf16(aq1, bk1, cacc, 0, 0, 0);
            sacc[n] = cacc;
        }

        // ---- scale, mask (register bits), tanh, zero-diag; write P bf16 ----
        #pragma unroll
        for (int n = 0; n < 4; ++n) {
            int col = n * 16 + l15;
            int gk  = k0 + col;
            #pragma unroll
            for (int r = 0; r < 4; ++r) {
                int qloc = qrow + quad * 4 + r;
                int gq = q0 + qloc;
                bool msk = ((half16 >> (n * 4 + r)) & 1u) == 0u;
                float sv = sacc[n][r] * 0.125f;       // 1/sqrt(64)
                float p = fast_tanh(msk ? -1e9f : sv);
                if (msk) p = -1.0f;
                if (gq == gk) p = 0.0f;               // ignore_diag
                if (gq >= SEQ || gk >= SEQ) p = 0.0f; // padding
                Ps[qloc * STRP + toff + col] = f2bf(p);
            }
        }

        // ---- PV (wave-private P rows: no barrier needed) ----
        const bf16x8 ap0 = *(const bf16x8*)&Ps[(qrow + l15) * STRP + toff + quad * 8];
        const bf16x8 ap1 = *(const bf16x8*)&Ps[(qrow + l15) * STRP + toff + 32 + quad * 8];
        #pragma unroll
        for (int dt = 0; dt < 4; ++dt) {
            bf16x8 bv0 = *(const bf16x8*)&Vs[(dt * 16 + l15) * STRB + quad * 8];
            bf16x8 bv1 = *(const bf16x8*)&Vs[(dt * 16 + l15) * STRB + 32 + quad * 8];
            oacc[dt] = __builtin_amdgcn_mfma_f32_16x16x32_bf16(ap0, bv0, oacc[dt], 0, 0, 0);
            oacc[dt] = __builtin_amdgcn_mfma_f32_16x16x32_bf16(ap1, bv1, oacc[dt], 0, 0, 0);
        }
    };

    // attention flush every 2 tiles: 512B row-chunks (vs 256B), half the stores
    auto flush = [&](int kt2) {
        const int kbase = kt2 * 128;
        #pragma unroll
        for (int i = 0; i < 4; ++i) {
            int row = prow + 4 * i;
            int gq  = q0 + row;
            if (gq >= SEQ) continue;
            int gk = kbase + l15 * 8;
            bf16x8 w = *(const bf16x8*)&Ps[row * STRP + l15 * 8];
            float f0 = bf2f((unsigned short)w[0]), f1 = bf2f((unsigned short)w[1]);
            float f2 = bf2f((unsigned short)w[2]), f3 = bf2f((unsigned short)w[3]);
            float f4 = bf2f((unsigned short)w[4]), f5 = bf2f((unsigned short)w[5]);
            float f6 = bf2f((unsigned short)w[6]), f7 = bf2f((unsigned short)w[7]);
            if (gk + 7 < SEQ) {
                f32x4a v0; v0[0]=f0; v0[1]=f1; v0[2]=f2; v0[3]=f3;
                f32x4a v1; v1[0]=f4; v1[1]=f5; v1[2]=f6; v1[3]=f7;
                *(f32x4a*)(Ab + (size_t)gq * SEQ + gk)     = v0;
                *(f32x4a*)(Ab + (size_t)gq * SEQ + gk + 4) = v1;
            } else {
                float fe[8] = {f0,f1,f2,f3,f4,f5,f6,f7};
                #pragma unroll
                for (int e = 0; e < 8; ++e)
                    if (gk + e < SEQ) Ab[(size_t)gq * SEQ + gk + e] = fe[e];
            }
        }
    };

    // shift-register over the 6 mask words -> all register indices static
    unsigned mw0 = mb[0], mw1 = mb[1], mw2 = mb[2], mw3 = mb[3], mw4 = mb[4], mw5 = mb[5];
    for (int kt2 = 0; kt2 < 6; ++kt2) {
        phase(2 * kt2,     mw0 & 0xffffu, 0);
        phase(2 * kt2 + 1, mw0 >> 16,     64);
        flush(kt2);
        mw0 = mw1; mw1 = mw2; mw2 = mw3; mw3 = mw4; mw4 = mw5;
    }

    // ---- O epilogue: Ks/Vs dead -> overlay-stage (wave-private rows),
    //      then row-contiguous float4 stores ----
    BAR();
    #pragma unroll
    for (int dt = 0; dt < 4; ++dt)
        #pragma unroll
        for (int r = 0; r < 4; ++r)
            Ostage[(qrow + quad * 4 + r) * OSTR + dt * 16 + l15] = oacc[dt][r];
    // wave-private strip: no further barrier needed
    #pragma unroll
    for (int i = 0; i < 4; ++i) {
        int row = prow + 4 * i;
        int gq  = q0 + row;
        f32x4 ov = *(const f32x4*)&Ostage[row * OSTR + pcol];
        if (gq < SEQ) *(f32x4*)(Ob + (size_t)gq * DIM + pcol) = ov;  // 16B-aligned
    }
}

extern "C" void kernel_launch(void* const* d_in, const int* in_sizes, int n_in,
                              void* d_out, int out_size, void* d_ws, size_t ws_size,
                              hipStream_t stream) {
    const float* Q = (const float*)d_in[0];
    const float* K = (const float*)d_in[1];
    const float* V = (const float*)d_in[2];
    const int*   M = (const int*)d_in[3];
    float* Out  = (float*)d_out;
    float* Attn = Out + (size_t)BATCH * SEQ * DIM;   // tuple order: (out, attention)
    dim3 grid(NT, BATCH);
    attn_kernel<<<grid, 256, 0, stream>>>(Q, K, V, M, Out, Attn);
}

// Round 8
// 324.926 us; speedup vs baseline: 1.0349x; 1.0223x over previous
//
#include <hip/hip_runtime.h>

#define BATCH 64
#define SEQ 729
#define DIM 64
#define NT 12       // k tiles of 64
#define STRB 72     // bf16 LDS row stride (Ks/Vs/Ps)
#define MSTR 68     // mask byte-row stride
#define OSTR 68     // epilogue fp32 dword-row stride

typedef __attribute__((ext_vector_type(8))) short bf16x8;
typedef __attribute__((ext_vector_type(4))) float f32x4;
// 4B-aligned vector views for the 729-strided global rows
typedef int   i32x4a __attribute__((ext_vector_type(4), aligned(4)));
typedef float f32x4a __attribute__((ext_vector_type(4), aligned(4)));

__device__ __forceinline__ unsigned short f2bf(float f) {
    unsigned int u = __float_as_uint(f);
    u += 0x7fffu + ((u >> 16) & 1u);   // round-to-nearest-even
    return (unsigned short)(u >> 16);
}

__device__ __forceinline__ unsigned long long pack4bf(float a, float b, float c, float d) {
    return (unsigned long long)f2bf(a)
         | ((unsigned long long)f2bf(b) << 16)
         | ((unsigned long long)f2bf(c) << 32)
         | ((unsigned long long)f2bf(d) << 48);
}

__device__ __forceinline__ float bf2f(unsigned int hi16) {
    return __uint_as_float(hi16 << 16);
}

// tanh(x) = 1 - 2/(exp2(2x*log2e)+1); fast_tanh(-1e9) = -1 exactly (exp2->0)
__device__ __forceinline__ float fast_tanh(float x) {
    float e = __builtin_amdgcn_exp2f(x * 2.88539008177792681f);
    return 1.0f - 2.0f * __builtin_amdgcn_rcpf(e + 1.0f);
}

// Raw barrier WITHOUT the __syncthreads() vmcnt(0) drain (round-5 win, keep):
// only LDS ops fenced; loads/stores stay in flight across phases; counted
// vmcnt at each register drain waits exactly what it needs.
#define BAR() do { \
    asm volatile("s_waitcnt lgkmcnt(0)" ::: "memory"); \
    __builtin_amdgcn_s_barrier(); \
    __builtin_amdgcn_sched_barrier(0); \
} while (0)

// launch_bounds(256,3): the only config the allocator handles cleanly
// (84 VGPR, no scratch — rounds 1-4 evidence). LDS 50432 -> 3 blocks/CU
// (same residency as the 131us round-5 baseline: clean A/B on structure).
__global__ __launch_bounds__(256, 3) void attn_kernel(
    const float* __restrict__ Qg, const float* __restrict__ Kg,
    const float* __restrict__ Vg, const int* __restrict__ Mg,
    float* __restrict__ Og, float* __restrict__ Ag)
{
    __shared__ __align__(16) unsigned char smem[50432];
    unsigned short* Ks0 = (unsigned short*)(smem);           // [k][d] bf16 (9216)
    unsigned short* Vs0 = (unsigned short*)(smem + 9216);    // [d][k] bf16 (9216)
    unsigned short* Ks1 = (unsigned short*)(smem + 18432);   // dbuf copies
    unsigned short* Vs1 = (unsigned short*)(smem + 27648);
    unsigned short* Ps  = (unsigned short*)(smem + 36864);   // Q bf16, then P bf16 (9216)
    unsigned char*  Mb8 = smem + 46080;                      // [q][k] mask bytes (4352)
    float* Ostage = (float*)smem;   // epilogue overlay on Ks0/Vs0 (17408 <= 18432)

    const int tid = threadIdx.x;
    const int q0  = blockIdx.x * 64;
    const int b   = blockIdx.y;

    const float* Qb = Qg + (size_t)b * SEQ * DIM;
    const float* Kb = Kg + (size_t)b * SEQ * DIM;
    const float* Vb = Vg + (size_t)b * SEQ * DIM;
    const int*   Mb = Mg + (size_t)b * SEQ * SEQ;
    float* Ob = Og + (size_t)b * SEQ * DIM;
    float* Ab = Ag + (size_t)b * SEQ * SEQ;

    const int lane = tid & 63;
    const int quad = lane >> 4;
    const int l15  = lane & 15;
    const int qrow = (tid >> 6) * 16;      // wave's q-strip base (local)

    // block-cooperative staging geometry: 16 consecutive threads cover one
    // row's 64 cols -> 256B contiguous segments, float4 per lane (KEEP:
    // round-1 showed smaller scalar segments amplify HBM traffic 5-10x)
    const int rr = tid >> 4;               // row group 0..15 (+16*i)
    const int cc = (tid & 15) * 4;         // col (floats)
    const int vd0 = (tid & 15) * 4;        // V: dims
    const int vk0 = (tid >> 4) * 4;        // V: k rows
    // wave-private row geometry: 16 lanes cover one row's 64 cols
    const int prow = qrow + (lane >> 4);   // + 4*i -> rows qrow..qrow+15
    const int pcol = (lane & 15) * 4;

    float4 kr[4], vr[4];
    i32x4a mr[4];

    auto load_k = [&](int k0n) {
        #pragma unroll
        for (int i = 0; i < 4; ++i) {
            int gk = k0n + rr + 16 * i;
            kr[i] = (gk < SEQ) ? *(const float4*)(Kb + gk * DIM + cc)
                               : float4{0, 0, 0, 0};
        }
    };
    auto load_v = [&](int k0n) {
        #pragma unroll
        for (int i = 0; i < 4; ++i) {
            int gk = k0n + vk0 + i;
            vr[i] = (gk < SEQ) ? *(const float4*)(Vb + gk * DIM + vd0)
                               : float4{0, 0, 0, 0};
        }
    };
    auto load_mask = [&](int k0n) {
        #pragma unroll
        for (int i = 0; i < 4; ++i) {
            int gq = q0 + prow + 4 * i;
            int gk = k0n + pcol;
            if (gq < SEQ && gk + 3 < SEQ) {
                mr[i] = *(const i32x4a*)(Mb + (size_t)gq * SEQ + gk);
            } else if (gq < SEQ) {
                i32x4a t;
                #pragma unroll
                for (int e = 0; e < 4; ++e)
                    t[e] = (gk + e < SEQ) ? Mb[(size_t)gq * SEQ + gk + e] : 0;
                mr[i] = t;
            } else {
                mr[i] = i32x4a{0, 0, 0, 0};
            }
        }
    };
    auto drain_mask = [&]() {   // pack 0/1 ints to bytes; wave-private rows
        #pragma unroll
        for (int i = 0; i < 4; ++i) {
            unsigned int mb = (unsigned)(mr[i][0] & 1)
                            | ((unsigned)(mr[i][1] & 1) << 8)
                            | ((unsigned)(mr[i][2] & 1) << 16)
                            | ((unsigned)(mr[i][3] & 1) << 24);
            *(unsigned int*)&Mb8[(prow + 4 * i) * MSTR + pcol] = mb;
        }
    };
    auto drain_kv = [&](unsigned short* Kd, unsigned short* Vd) {
        #pragma unroll
        for (int i = 0; i < 4; ++i)
            *(unsigned long long*)&Kd[(rr + 16 * i) * STRB + cc] =
                pack4bf(kr[i].x, kr[i].y, kr[i].z, kr[i].w);
        #pragma unroll
        for (int j = 0; j < 4; ++j) {
            float v0 = j==0?vr[0].x:j==1?vr[0].y:j==2?vr[0].z:vr[0].w;
            float v1 = j==0?vr[1].x:j==1?vr[1].y:j==2?vr[1].z:vr[1].w;
            float v2 = j==0?vr[2].x:j==1?vr[2].y:j==2?vr[2].z:vr[2].w;
            float v3 = j==0?vr[3].x:j==1?vr[3].y:j==2?vr[3].z:vr[3].w;
            *(unsigned long long*)&Vd[(vd0 + j) * STRB + vk0] = pack4bf(v0, v1, v2, v3);
        }
    };

    // ---- prologue: issue tile-0 loads first (max lead), stage Q ----
    load_k(0); load_v(0); load_mask(0);
    #pragma unroll
    for (int i = 0; i < 4; ++i) {
        int gq = q0 + rr + 16 * i;
        float4 x = (gq < SEQ) ? *(const float4*)(Qb + gq * DIM + cc)
                              : float4{0, 0, 0, 0};
        *(unsigned long long*)&Ps[(rr + 16 * i) * STRB + cc] = pack4bf(x.x, x.y, x.z, x.w);
    }
    BAR();   // Qs visible (lgkmcnt only)

    // hoist loop-invariant Q fragments; Ps becomes the P bf16 buffer
    const bf16x8 aq0 = *(const bf16x8*)&Ps[(qrow + l15) * STRB + quad * 8];
    const bf16x8 aq1 = *(const bf16x8*)&Ps[(qrow + l15) * STRB + 32 + quad * 8];

    // drain tile 0 -> buf0; issue tile-1 loads
    drain_mask();
    drain_kv(Ks0, Vs0);
    load_k(64); load_v(64); load_mask(64);
    BAR();   // buf0 visible

    f32x4 oacc[4];
    #pragma unroll
    for (int dt = 0; dt < 4; ++dt) {
        oacc[dt][0]=0.f; oacc[dt][1]=0.f; oacc[dt][2]=0.f; oacc[dt][3]=0.f;
    }

    for (int t = 0; t < NT; ++t) {
        const int k0 = t * 64;
        const unsigned short* KsC = (t & 1) ? Ks1 : Ks0;   // uniform selects
        const unsigned short* VsC = (t & 1) ? Vs1 : Vs0;
        unsigned short* KsN = (t & 1) ? Ks0 : Ks1;
        unsigned short* VsN = (t & 1) ? Vs0 : Vs1;

        // ---- QK^T (starts immediately at phase start: no drain ahead) ----
        f32x4 sacc[4];
        #pragma unroll
        for (int n = 0; n < 4; ++n) {
            bf16x8 bk0 = *(const bf16x8*)&KsC[(n * 16 + l15) * STRB + quad * 8];
            bf16x8 bk1 = *(const bf16x8*)&KsC[(n * 16 + l15) * STRB + 32 + quad * 8];
            f32x4 c; c[0]=0.f; c[1]=0.f; c[2]=0.f; c[3]=0.f;
            c = __builtin_amdgcn_mfma_f32_16x16x32_bf16(aq0, bk0, c, 0, 0, 0);
            c = __builtin_amdgcn_mfma_f32_16x16x32_bf16(aq1, bk1, c, 0, 0, 0);
            sacc[n] = c;
        }

        // ---- scale, mask (LDS bytes), tanh, zero-diag; write P bf16 ----
        #pragma unroll
        for (int n = 0; n < 4; ++n) {
            int col = n * 16 + l15;
            int gk  = k0 + col;
            #pragma unroll
            for (int r = 0; r < 4; ++r) {
                int qloc = qrow + quad * 4 + r;
                int gq = q0 + qloc;
                int m = Mb8[qloc * MSTR + col];
                float sv = sacc[n][r] * 0.125f;        // 1/sqrt(64)
                // masked: tanh(-1e9) == -1 exactly via exp2 underflow
                float p = fast_tanh((m == 0) ? -1e9f : sv);
                if (gq == gk || gk >= SEQ) p = 0.0f;   // ignore_diag + padding
                Ps[qloc * STRB + col] = f2bf(p);
            }
        }

        // ---- PV (wave-private P rows: no barrier needed) ----
        const bf16x8 ap0 = *(const bf16x8*)&Ps[(qrow + l15) * STRB + quad * 8];
        const bf16x8 ap1 = *(const bf16x8*)&Ps[(qrow + l15) * STRB + 32 + quad * 8];
        #pragma unroll
        for (int dt = 0; dt < 4; ++dt) {
            bf16x8 bv0 = *(const bf16x8*)&VsC[(dt * 16 + l15) * STRB + quad * 8];
            bf16x8 bv1 = *(const bf16x8*)&VsC[(dt * 16 + l15) * STRB + 32 + quad * 8];
            oacc[dt] = __builtin_amdgcn_mfma_f32_16x16x32_bf16(ap0, bv0, oacc[dt], 0, 0, 0);
            oacc[dt] = __builtin_amdgcn_mfma_f32_16x16x32_bf16(ap1, bv1, oacc[dt], 0, 0, 0);
        }

        // ---- attention write-out from bf16 P (values PV consumes):
        //      wave-private rows, row-contiguous float4 -> 256B segments ----
        #pragma unroll
        for (int i = 0; i < 4; ++i) {
            int row = prow + 4 * i;
            int gq  = q0 + row;
            int gk  = k0 + pcol;
            unsigned long long w = *(const unsigned long long*)&Ps[row * STRB + pcol];
            f32x4 pv;
            pv[0] = bf2f((unsigned)(w      ) & 0xffffu);
            pv[1] = bf2f((unsigned)(w >> 16) & 0xffffu);
            pv[2] = bf2f((unsigned)(w >> 32) & 0xffffu);
            pv[3] = bf2f((unsigned)(w >> 48) & 0xffffu);
            if (gq < SEQ) {
                if (gk + 3 < SEQ) {
                    *(f32x4a*)(Ab + (size_t)gq * SEQ + gk) = pv;
                } else {
                    #pragma unroll
                    for (int e = 0; e < 4; ++e)
                        if (gk + e < SEQ) Ab[(size_t)gq * SEQ + gk + e] = pv[e];
                }
            }
        }

        // ---- drain tile t+1 into the other buffer (vmcnt wait had a full
        //      compute phase of lead), then issue tile t+2 loads ----
        if (t + 1 < NT) {
            drain_mask();
            drain_kv(KsN, VsN);
            if (t + 2 < NT) {
                load_k(k0 + 128); load_v(k0 + 128); load_mask(k0 + 128);
            }
            BAR();   // single barrier per phase: writes visible; readers of
                     // the buffer we'll overwrite next phase are done (see
                     // ordering argument in commit notes)
        }
    }

    // ---- O epilogue: all waves done with Ks/Vs -> overlay-stage
    //      (wave-private rows), then row-contiguous float4 stores ----
    BAR();
    #pragma unroll
    for (int dt = 0; dt < 4; ++dt)
        #pragma unroll
        for (int r = 0; r < 4; ++r)
            Ostage[(qrow + quad * 4 + r) * OSTR + dt * 16 + l15] = oacc[dt][r];
    // wave-private strip: no further barrier needed
    #pragma unroll
    for (int i = 0; i < 4; ++i) {
        int row = prow + 4 * i;
        int gq  = q0 + row;
        f32x4 ov = *(const f32x4*)&Ostage[row * OSTR + pcol];
        if (gq < SEQ) *(f32x4*)(Ob + (size_t)gq * DIM + pcol) = ov;  // 16B-aligned
    }
}

extern "C" void kernel_launch(void* const* d_in, const int* in_sizes, int n_in,
                              void* d_out, int out_size, void* d_ws, size_t ws_size,
                              hipStream_t stream) {
    const float* Q = (const float*)d_in[0];
    const float* K = (const float*)d_in[1];
    const float* V = (const float*)d_in[2];
    const int*   M = (const int*)d_in[3];
    float* Out  = (float*)d_out;
    float* Attn = Out + (size_t)BATCH * SEQ * DIM;   // tuple order: (out, attention)
    dim3 grid(NT, BATCH);
    attn_kernel<<<grid, 256, 0, stream>>>(Q, K, V, M, Out, Attn);
}